// Round 12
// baseline (55.976 us; speedup 1.0000x reference)
//
#include <hip/hip_runtime.h>
#include <math.h>
#include <stdint.h>

#define IN_C 64
#define OUT_C 128
#define H 56
#define W 56
#define NB 32
#define HW (H*W)
#define KK 576          // IN_C*9
#define EPS 1e-12f
#define PH 58           // padded rows
#define PW 66           // padded cols in xcl (only 0..57 staged/used by conv)

#define XT_BYTES 44544                   // 6 rows x 58 cols x 64c x 2B
#define WSLOT 16384                      // one tap: 128v x 64c x 2B
#define CONV_LDS (XT_BYTES + 3 * WSLOT)  // 93696 B

typedef _Float16 half8 __attribute__((ext_vector_type(8)));
typedef float f32x4 __attribute__((ext_vector_type(4)));
typedef unsigned int u32;
typedef const u32 __attribute__((address_space(1)))* gp_t;
typedef u32 __attribute__((address_space(3)))* sp_t;

// ---------------- kernel 1: transpose to channels-last padded fp16 ----------
__global__ __launch_bounds__(256) void k_xpose(const float* __restrict__ x,
                                               _Float16* __restrict__ xcl,
                                               float* __restrict__ s) {
    __shared__ float lds[64][59];
    int n = blockIdx.y, pr = blockIdx.x;
    int tid = threadIdx.x;
    int h = pr - 1;
    bool rowz = (h < 0 || h >= H);
    {
        int w = tid & 63, c4 = tid >> 6;
        if (!rowz && w < 56) {
#pragma unroll
            for (int cg = 0; cg < 16; ++cg) {
                int c = cg * 4 + c4;
                lds[c][w] = x[((size_t)(n * IN_C + c)) * HW + h * W + w];
            }
        }
    }
    __syncthreads();
    int c = tid & 63, pg = tid >> 6;
    _Float16* dst = xcl + ((size_t)n * PH + pr) * PW * IN_C;
#pragma unroll
    for (int pcg = 0; pcg < 15; ++pcg) {
        int pc = pcg * 4 + pg;          // only cols 0..57 are consumed
        if (pc >= 58) break;
        int w = pc - 1;
        bool valid = (!rowz && (unsigned)w < W);
        float val = valid ? lds[c][w] : 0.f;
        dst[(size_t)pc * IN_C + (c ^ ((pc & 7) << 3))] = (_Float16)val;
        float sq = val * val;
#pragma unroll
        for (int off = 32; off > 0; off >>= 1) sq += __shfl_xor(sq, off);
        if (valid && c == 0) s[(size_t)n * HW + h * W + w] = sq;
    }
}

// ---------------- kernel 2: 3x3 neighborhood sum -> 1/x_norm ----------------
__global__ __launch_bounds__(256) void k_xnorm(const float* __restrict__ s,
                                               const float* __restrict__ q,
                                               float* __restrict__ inv_xn) {
    int t = blockIdx.x * 256 + threadIdx.x;
    if (t >= NB * HW / 4) return;
    int n = t / (HW / 4);
    int rem = t - n * (HW / 4);
    int p0 = rem * 4;
    int h = p0 / W, w0 = p0 - h * W;
    float q2 = q[0] * 0.01f;
    q2 = q2 * q2;
    const float* sp = s + (size_t)n * HW;
    float a0 = 0.f, a1 = 0.f, a2 = 0.f, a3 = 0.f;
#pragma unroll
    for (int dy = -1; dy <= 1; ++dy) {
        int y = h + dy;
        if ((unsigned)y >= H) continue;
        const float* row = sp + y * W;
        float4 m = *(const float4*)(row + w0);
        float lft = (w0 > 0) ? row[w0 - 1] : 0.f;
        float rgt = (w0 + 4 < W) ? row[w0 + 4] : 0.f;
        a0 += lft + m.x + m.y;
        a1 += m.x + m.y + m.z;
        a2 += m.y + m.z + m.w;
        a3 += m.z + m.w + rgt;
    }
    float4 res;
    res.x = 1.f / (sqrtf(a0 + EPS) + q2);
    res.y = 1.f / (sqrtf(a1 + EPS) + q2);
    res.z = 1.f / (sqrtf(a2 + EPS) + q2);
    res.w = 1.f / (sqrtf(a3 + EPS) + q2);
    *(float4*)(inv_xn + (size_t)n * HW + p0) = res;
}

// ---------------- kernel 3: weight prep (swizzled) ---------------------------
__global__ __launch_bounds__(64) void k_wprep(const float* __restrict__ w,
                                              const float* __restrict__ p,
                                              const float* __restrict__ q,
                                              _Float16* __restrict__ wt,
                                              float* __restrict__ e) {
    int v = blockIdx.x;
    int lane = threadIdx.x;          // lane = c
    const float* wv = w + v * KK;
    float acc = 0.f;
#pragma unroll
    for (int j = 0; j < 9; ++j) {
        float t = wv[lane * 9 + j];
        acc += t * t;
    }
#pragma unroll
    for (int off = 32; off > 0; off >>= 1) acc += __shfl_xor(acc, off);
    float q2 = q[0] * 0.01f;
    q2 = q2 * q2;
    float inv = 1.f / (sqrtf(acc + EPS) + q2);
    int cs = lane ^ ((v & 7) << 3);
#pragma unroll
    for (int l = 0; l < 9; ++l) {
        wt[((size_t)l * OUT_C + v) * IN_C + cs] = (_Float16)(wv[lane * 9 + l] * inv);
    }
    if (lane == 0) e[v] = p[v] * p[v] * 0.01f;
}

// ---------------- kernel 4: MFMA conv, asm-pipelined -------------------------
// Frag reads are inline-asm ds_read_b128 issued ONE TAP AHEAD (unsinkable);
// weight DMA is 3-slot ring issued TWO taps ahead with counted vmcnt.
// Per iter: MFMA(l) | barrier | WDMA(l+3) | lgkm(0)+SB -> frags(l+1) |
//           vmcnt(2) | barrier | asm-reads(l+2).
__global__ __launch_bounds__(512, 2) void k_conv_mfma(
    const _Float16* __restrict__ xcl,   // [NB][PH][PW][64] swizzled
    const _Float16* __restrict__ wt,    // [9][128][64] swizzled
    const float* __restrict__ inv_xn,   // [NB][HW]
    const float* __restrict__ e,        // [128]
    float* __restrict__ out)            // [NB][128][HW]
{
    extern __shared__ __align__(16) char smem[];
    char* xls = smem;                    // [6][58][64] halves (swizzled cols)
    char* wls = smem + XT_BYTES;         // 3 x [128][64] halves (tap ring)

    int tid = threadIdx.x;
    int wv = tid >> 6;
    int lane = tid & 63;
    int l15 = lane & 15;
    int kg = lane >> 4;

    int flat = blockIdx.y * 14 + blockIdx.x;
    int sw = (flat & 7) * 56 + (flat >> 3);   // bijective XCD swizzle (448)
    int n = sw / 14;
    int rc = sw - n * 14;
    int r0 = rc * 4;
    int row_rel = wv >> 1;
    int vh = wv & 1;
    int wave_chunk = wv * 64;

#define WDMA(t) do {                                                          \
        const char* wsrc_ = (const char*)wt + (size_t)(t) * WSLOT;            \
        char* wdst_ = wls + ((t) % 3) * WSLOT;                                \
        __builtin_amdgcn_global_load_lds((gp_t)(wsrc_ + tid * 16),            \
            (sp_t)(wdst_ + wave_chunk * 16), 16, 0, 0);                       \
        __builtin_amdgcn_global_load_lds((gp_t)(wsrc_ + (512 + tid) * 16),    \
            (sp_t)(wdst_ + (512 + wave_chunk) * 16), 16, 0, 0);               \
    } while (0)

    // ---- prologue: x-tile DMA + w taps 0,1,2
    {
        const char* xsrc = (const char*)(xcl + ((size_t)n * PH + r0) * PW * IN_C);
#pragma unroll
        for (int i = 0; i < 6; ++i) {
            int j = i * 512 + tid;
            if (j < 2784) {
                int row = j / 464;
                int off = j - row * 464;
                __builtin_amdgcn_global_load_lds(
                    (gp_t)(xsrc + row * (PW * IN_C * 2) + off * 16),
                    (sp_t)(xls + (i * 512 + wave_chunk) * 16), 16, 0, 0);
            }
        }
        WDMA(0); WDMA(1); WDMA(2);
    }
    asm volatile("s_waitcnt vmcnt(2)" ::: "memory");  // x,w0,w1 landed; w2 flies
    __builtin_amdgcn_s_barrier();

    u32 xb32 = (u32)(uintptr_t)(sp_t)xls;
    u32 wb32 = (u32)(uintptr_t)(sp_t)wls;

    half8 fa[2][2][4];   // [parity][k][mt]
    half8 fb[2][2][4];   // [parity][k][vt]

#define ISSUE_READS(t) do {                                                   \
        const int di_ = (t) / 3, dj_ = (t) % 3;                               \
        int pc0_ = l15 + dj_;                                                 \
        u32 xa_ = xb32 + (u32)(((row_rel + di_) * 58 + pc0_) * 128);          \
        int xk_ = (pc0_ & 7) << 4;                                            \
        u32 wa_ = wb32 + (u32)(((t) % 3) * WSLOT + (vh * 64 + l15) * 128);    \
        int wk_ = (l15 & 7) << 4;                                             \
        _Pragma("unroll") for (int k_ = 0; k_ < 2; ++k_) {                    \
            int ko_ = k_ * 64 + kg * 16;                                      \
            _Pragma("unroll") for (int mt_ = 0; mt_ < 4; ++mt_)               \
                asm volatile("ds_read_b128 %0, %1"                            \
                    : "=v"(fa[(t) & 1][k_][mt_])                              \
                    : "v"(xa_ + (u32)(mt_ * 2048) + (u32)(ko_ ^ xk_)));       \
            _Pragma("unroll") for (int vt_ = 0; vt_ < 4; ++vt_)               \
                asm volatile("ds_read_b128 %0, %1"                            \
                    : "=v"(fb[(t) & 1][k_][vt_])                              \
                    : "v"(wa_ + (u32)(vt_ * 2048) + (u32)(ko_ ^ wk_)));       \
        }                                                                     \
    } while (0)

    ISSUE_READS(0);
    ISSUE_READS(1);
    // frags(0) ready: 32 outstanding, wait until <=15 (gfx9 lgkmcnt max is 15;
    // ds_reads complete in order so this covers tap 0's 16 + 1 of tap 1)
    asm volatile("s_waitcnt lgkmcnt(15)" ::: "memory");
    __builtin_amdgcn_sched_barrier(0);

    f32x4 acc[4][4];
#pragma unroll
    for (int mt = 0; mt < 4; ++mt)
#pragma unroll
        for (int vt = 0; vt < 4; ++vt) acc[mt][vt] = (f32x4){0.f, 0.f, 0.f, 0.f};

#pragma unroll
    for (int l = 0; l < 9; ++l) {
        __builtin_amdgcn_s_setprio(1);
#pragma unroll
        for (int k = 0; k < 2; ++k)
#pragma unroll
            for (int vt = 0; vt < 4; ++vt)
#pragma unroll
                for (int mt = 0; mt < 4; ++mt)
                    acc[mt][vt] = __builtin_amdgcn_mfma_f32_16x16x32_f16(
                        fa[l & 1][k][mt], fb[l & 1][k][vt], acc[mt][vt], 0, 0, 0);
        __builtin_amdgcn_s_setprio(0);

        __builtin_amdgcn_s_barrier();        // slot l%3 free (all waves)
        if (l + 3 <= 8) WDMA(l + 3);         // refill freed slot, 2 taps ahead
        if (l < 8) {
            asm volatile("s_waitcnt lgkmcnt(0)" ::: "memory");  // frags(l+1)
            __builtin_amdgcn_sched_barrier(0);
        }
        if (l + 2 <= 8) {
            if (l + 3 <= 8) asm volatile("s_waitcnt vmcnt(2)" ::: "memory");
            else            asm volatile("s_waitcnt vmcnt(0)" ::: "memory");
            __builtin_amdgcn_s_barrier();    // slot (l+2)%3 visible to all
            ISSUE_READS(l + 2);              // fly under MFMA(l+1)
        }
    }
#undef ISSUE_READS
#undef WDMA

    // ---- epilogue: lane holds cols mt*16+kg*4..+3 for v = vh*64+vt*16+l15
    int r = r0 + row_rel;
    const float* ixrow = inv_xn + (size_t)n * HW + r * W;
#pragma unroll
    for (int mt = 0; mt < 4; ++mt) {
        int col0 = mt * 16 + kg * 4;
        if (col0 >= W) continue;
        float4 ixn = *(const float4*)(ixrow + col0);
        const float* ixp = &ixn.x;
#pragma unroll
        for (int vt = 0; vt < 4; ++vt) {
            int v = vh * 64 + vt * 16 + l15;
            float ev = e[v];
            float4 res;
            float* rp = &res.x;
            if (fabsf(ev - 2.0f) < 1e-4f) {
#pragma unroll
                for (int j = 0; j < 4; ++j) {
                    float z = acc[mt][vt][j] * ixp[j];
                    float mag = fabsf(z) + EPS;
                    rp[j] = copysignf(mag * mag, z);
                }
            } else {
#pragma unroll
                for (int j = 0; j < 4; ++j) {
                    float z = acc[mt][vt][j] * ixp[j];
                    float mag = fabsf(z) + EPS;
                    float pw = exp2f(ev * log2f(mag));
                    rp[j] = copysignf(pw, z);
                }
            }
            *(float4*)(out + ((size_t)n * OUT_C + v) * HW + r * W + col0) = res;
        }
    }
}

// ---------------- launch ----------------------------------------------------
extern "C" void kernel_launch(void* const* d_in, const int* in_sizes, int n_in,
                              void* d_out, int out_size, void* d_ws, size_t ws_size,
                              hipStream_t stream) {
    const float* x = (const float*)d_in[0];
    const float* w = (const float*)d_in[1];
    const float* p = (const float*)d_in[2];
    const float* q = (const float*)d_in[3];
    float* out = (float*)d_out;

    char* ws = (char*)d_ws;
    float*    s      = (float*)ws;                              // 100352 f
    float*    inv_xn = (float*)(ws + 401408);                   // 100352 f
    float*    e      = (float*)(ws + 802816);                   // 128 f
    _Float16* wt     = (_Float16*)(ws + 803328);                // 9*128*64 h
    _Float16* xcl    = (_Float16*)(ws + 950784);                // 32*58*66*64 h

    (void)hipFuncSetAttribute((const void*)k_conv_mfma,
                        hipFuncAttributeMaxDynamicSharedMemorySize, CONV_LDS);

    k_xpose<<<dim3(PH, NB), dim3(256), 0, stream>>>(x, xcl, s);
    k_xnorm<<<dim3(NB * HW / 4 / 256), dim3(256), 0, stream>>>(s, q, inv_xn);
    k_wprep<<<dim3(OUT_C), dim3(64), 0, stream>>>(w, p, q, wt, e);
    k_conv_mfma<<<dim3(14, NB), dim3(512), CONV_LDS, stream>>>(
        xcl, wt, inv_xn, e, out);
}

// Round 13
// 55.565 us; speedup vs baseline: 1.0074x; 1.0074x over previous
//
#include <hip/hip_runtime.h>
#include <math.h>
#include <stdint.h>

#define IN_C 64
#define OUT_C 128
#define H 56
#define W 56
#define NB 32
#define HW (H*W)
#define KK 576          // IN_C*9
#define EPS 1e-12f
#define PH 58           // padded rows
#define PW 66           // padded cols in xcl (only 0..57 staged/used by conv)

#define XT_BYTES 44544                   // 6 rows x 58 cols x 64c x 2B
#define WSLOT 16384                      // one tap: 128v x 64c x 2B
#define CONV_LDS (XT_BYTES + 2 * WSLOT)  // 77312 B -> 2 blocks/CU

typedef _Float16 half8 __attribute__((ext_vector_type(8)));
typedef float f32x4 __attribute__((ext_vector_type(4)));
typedef unsigned int u32;
typedef const u32 __attribute__((address_space(1)))* gp_t;
typedef u32 __attribute__((address_space(3)))* sp_t;

// ---------------- kernel 1: transpose to channels-last padded fp16 ----------
__global__ __launch_bounds__(256) void k_xpose(const float* __restrict__ x,
                                               _Float16* __restrict__ xcl,
                                               float* __restrict__ s) {
    __shared__ float lds[64][59];
    int n = blockIdx.y, pr = blockIdx.x;
    int tid = threadIdx.x;
    int h = pr - 1;
    bool rowz = (h < 0 || h >= H);
    {
        int w = tid & 63, c4 = tid >> 6;
        if (!rowz && w < 56) {
#pragma unroll
            for (int cg = 0; cg < 16; ++cg) {
                int c = cg * 4 + c4;
                lds[c][w] = x[((size_t)(n * IN_C + c)) * HW + h * W + w];
            }
        }
    }
    __syncthreads();
    int c = tid & 63, pg = tid >> 6;
    _Float16* dst = xcl + ((size_t)n * PH + pr) * PW * IN_C;
#pragma unroll
    for (int pcg = 0; pcg < 15; ++pcg) {
        int pc = pcg * 4 + pg;          // only cols 0..57 are consumed
        if (pc >= 58) break;
        int w = pc - 1;
        bool valid = (!rowz && (unsigned)w < W);
        float val = valid ? lds[c][w] : 0.f;
        dst[(size_t)pc * IN_C + (c ^ ((pc & 7) << 3))] = (_Float16)val;
        float sq = val * val;
#pragma unroll
        for (int off = 32; off > 0; off >>= 1) sq += __shfl_xor(sq, off);
        if (valid && c == 0) s[(size_t)n * HW + h * W + w] = sq;
    }
}

// ---------------- kernel 2: 3x3 neighborhood sum -> 1/x_norm ----------------
__global__ __launch_bounds__(256) void k_xnorm(const float* __restrict__ s,
                                               const float* __restrict__ q,
                                               float* __restrict__ inv_xn) {
    int t = blockIdx.x * 256 + threadIdx.x;
    if (t >= NB * HW / 4) return;
    int n = t / (HW / 4);
    int rem = t - n * (HW / 4);
    int p0 = rem * 4;
    int h = p0 / W, w0 = p0 - h * W;
    float q2 = q[0] * 0.01f;
    q2 = q2 * q2;
    const float* sp = s + (size_t)n * HW;
    float a0 = 0.f, a1 = 0.f, a2 = 0.f, a3 = 0.f;
#pragma unroll
    for (int dy = -1; dy <= 1; ++dy) {
        int y = h + dy;
        if ((unsigned)y >= H) continue;
        const float* row = sp + y * W;
        float4 m = *(const float4*)(row + w0);
        float lft = (w0 > 0) ? row[w0 - 1] : 0.f;
        float rgt = (w0 + 4 < W) ? row[w0 + 4] : 0.f;
        a0 += lft + m.x + m.y;
        a1 += m.x + m.y + m.z;
        a2 += m.y + m.z + m.w;
        a3 += m.z + m.w + rgt;
    }
    float4 res;
    res.x = 1.f / (sqrtf(a0 + EPS) + q2);
    res.y = 1.f / (sqrtf(a1 + EPS) + q2);
    res.z = 1.f / (sqrtf(a2 + EPS) + q2);
    res.w = 1.f / (sqrtf(a3 + EPS) + q2);
    *(float4*)(inv_xn + (size_t)n * HW + p0) = res;
}

// ---------------- kernel 3: weight prep (swizzled) ---------------------------
__global__ __launch_bounds__(64) void k_wprep(const float* __restrict__ w,
                                              const float* __restrict__ p,
                                              const float* __restrict__ q,
                                              _Float16* __restrict__ wt,
                                              float* __restrict__ e) {
    int v = blockIdx.x;
    int lane = threadIdx.x;          // lane = c
    const float* wv = w + v * KK;
    float acc = 0.f;
#pragma unroll
    for (int j = 0; j < 9; ++j) {
        float t = wv[lane * 9 + j];
        acc += t * t;
    }
#pragma unroll
    for (int off = 32; off > 0; off >>= 1) acc += __shfl_xor(acc, off);
    float q2 = q[0] * 0.01f;
    q2 = q2 * q2;
    float inv = 1.f / (sqrtf(acc + EPS) + q2);
    int cs = lane ^ ((v & 7) << 3);
#pragma unroll
    for (int l = 0; l < 9; ++l) {
        wt[((size_t)l * OUT_C + v) * IN_C + cs] = (_Float16)(wv[lane * 9 + l] * inv);
    }
    if (lane == 0) e[v] = p[v] * p[v] * 0.01f;
}

// ---------------- kernel 4: MFMA conv, asm-pipelined, 2 blocks/CU ------------
// Per iter: lgkm(0) | vmcnt(0)+barrier | WDMA(l+2) | asm-reads(l+1) | MFMA(l).
// One barrier/tap; reads fly under MFMA; DMA has 2 taps of cover.
__global__ __launch_bounds__(512, 2) void k_conv_mfma(
    const _Float16* __restrict__ xcl,   // [NB][PH][PW][64] swizzled
    const _Float16* __restrict__ wt,    // [9][128][64] swizzled
    const float* __restrict__ inv_xn,   // [NB][HW]
    const float* __restrict__ e,        // [128]
    float* __restrict__ out)            // [NB][128][HW]
{
    extern __shared__ __align__(16) char smem[];
    char* xls = smem;                    // [6][58][64] halves (swizzled cols)
    char* wls = smem + XT_BYTES;         // 2 x [128][64] halves (tap ring)

    int tid = threadIdx.x;
    int wv = tid >> 6;
    int lane = tid & 63;
    int l15 = lane & 15;
    int kg = lane >> 4;

    int flat = blockIdx.y * 14 + blockIdx.x;
    int sw = (flat & 7) * 56 + (flat >> 3);   // bijective XCD swizzle (448)
    int n = sw / 14;
    int rc = sw - n * 14;
    int r0 = rc * 4;
    int row_rel = wv >> 1;
    int vh = wv & 1;
    int wave_chunk = wv * 64;

#define WDMA(t) do {                                                          \
        const char* wsrc_ = (const char*)wt + (size_t)(t) * WSLOT;            \
        char* wdst_ = wls + ((t) & 1) * WSLOT;                                \
        __builtin_amdgcn_global_load_lds((gp_t)(wsrc_ + tid * 16),            \
            (sp_t)(wdst_ + wave_chunk * 16), 16, 0, 0);                       \
        __builtin_amdgcn_global_load_lds((gp_t)(wsrc_ + (512 + tid) * 16),    \
            (sp_t)(wdst_ + (512 + wave_chunk) * 16), 16, 0, 0);               \
    } while (0)

    // ---- prologue: x-tile DMA + w taps 0,1
    {
        const char* xsrc = (const char*)(xcl + ((size_t)n * PH + r0) * PW * IN_C);
#pragma unroll
        for (int i = 0; i < 6; ++i) {
            int j = i * 512 + tid;
            if (j < 2784) {
                int row = j / 464;
                int off = j - row * 464;
                __builtin_amdgcn_global_load_lds(
                    (gp_t)(xsrc + row * (PW * IN_C * 2) + off * 16),
                    (sp_t)(xls + (i * 512 + wave_chunk) * 16), 16, 0, 0);
            }
        }
        WDMA(0); WDMA(1);
    }
    asm volatile("s_waitcnt vmcnt(2)" ::: "memory");  // x + w0 landed; w1 flies
    __builtin_amdgcn_s_barrier();

    u32 xb32 = (u32)(uintptr_t)(sp_t)xls;
    u32 wb32 = (u32)(uintptr_t)(sp_t)wls;

    half8 fa[2][2][4];   // [parity][k][mt]
    half8 fb[2][2][4];   // [parity][k][vt]

#define ISSUE_READS(t) do {                                                   \
        const int di_ = (t) / 3, dj_ = (t) % 3;                               \
        int pc0_ = l15 + dj_;                                                 \
        u32 xa_ = xb32 + (u32)(((row_rel + di_) * 58 + pc0_) * 128);          \
        int xk_ = (pc0_ & 7) << 4;                                            \
        u32 wa_ = wb32 + (u32)(((t) & 1) * WSLOT + (vh * 64 + l15) * 128);    \
        int wk_ = (l15 & 7) << 4;                                             \
        _Pragma("unroll") for (int k_ = 0; k_ < 2; ++k_) {                    \
            int ko_ = k_ * 64 + kg * 16;                                      \
            _Pragma("unroll") for (int mt_ = 0; mt_ < 4; ++mt_)               \
                asm volatile("ds_read_b128 %0, %1"                            \
                    : "=v"(fa[(t) & 1][k_][mt_])                              \
                    : "v"(xa_ + (u32)(mt_ * 2048) + (u32)(ko_ ^ xk_)));       \
            _Pragma("unroll") for (int vt_ = 0; vt_ < 4; ++vt_)               \
                asm volatile("ds_read_b128 %0, %1"                            \
                    : "=v"(fb[(t) & 1][k_][vt_])                              \
                    : "v"(wa_ + (u32)(vt_ * 2048) + (u32)(ko_ ^ wk_)));       \
        }                                                                     \
    } while (0)

    ISSUE_READS(0);      // w0 + x are in LDS

    f32x4 acc[4][4];
#pragma unroll
    for (int mt = 0; mt < 4; ++mt)
#pragma unroll
        for (int vt = 0; vt < 4; ++vt) acc[mt][vt] = (f32x4){0.f, 0.f, 0.f, 0.f};

#pragma unroll
    for (int l = 0; l < 9; ++l) {
        // frags(l) ready; own ds queue drained
        asm volatile("s_waitcnt lgkmcnt(0)" ::: "memory");
        __builtin_amdgcn_sched_barrier(0);
        // w(l+1) landed; all waves' reads of slot l&1 done
        asm volatile("s_waitcnt vmcnt(0)" ::: "memory");
        __builtin_amdgcn_s_barrier();

        if (l + 2 <= 8) WDMA(l + 2);         // into slot l&1 (now safe)
        if (l + 1 <= 8) ISSUE_READS(l + 1);  // fly under MFMA(l)

        __builtin_amdgcn_s_setprio(1);
#pragma unroll
        for (int k = 0; k < 2; ++k)
#pragma unroll
            for (int vt = 0; vt < 4; ++vt)
#pragma unroll
                for (int mt = 0; mt < 4; ++mt)
                    acc[mt][vt] = __builtin_amdgcn_mfma_f32_16x16x32_f16(
                        fa[l & 1][k][mt], fb[l & 1][k][vt], acc[mt][vt], 0, 0, 0);
        __builtin_amdgcn_s_setprio(0);
    }
#undef ISSUE_READS
#undef WDMA

    // ---- epilogue: lane holds cols mt*16+kg*4..+3 for v = vh*64+vt*16+l15
    int r = r0 + row_rel;
    const float* ixrow = inv_xn + (size_t)n * HW + r * W;
#pragma unroll
    for (int mt = 0; mt < 4; ++mt) {
        int col0 = mt * 16 + kg * 4;
        if (col0 >= W) continue;
        float4 ixn = *(const float4*)(ixrow + col0);
        const float* ixp = &ixn.x;
#pragma unroll
        for (int vt = 0; vt < 4; ++vt) {
            int v = vh * 64 + vt * 16 + l15;
            float ev = e[v];
            float4 res;
            float* rp = &res.x;
            if (fabsf(ev - 2.0f) < 1e-4f) {
#pragma unroll
                for (int j = 0; j < 4; ++j) {
                    float z = acc[mt][vt][j] * ixp[j];
                    float mag = fabsf(z) + EPS;
                    rp[j] = copysignf(mag * mag, z);
                }
            } else {
#pragma unroll
                for (int j = 0; j < 4; ++j) {
                    float z = acc[mt][vt][j] * ixp[j];
                    float mag = fabsf(z) + EPS;
                    float pw = exp2f(ev * log2f(mag));
                    rp[j] = copysignf(pw, z);
                }
            }
            *(float4*)(out + ((size_t)n * OUT_C + v) * HW + r * W + col0) = res;
        }
    }
}

// ---------------- launch ----------------------------------------------------
extern "C" void kernel_launch(void* const* d_in, const int* in_sizes, int n_in,
                              void* d_out, int out_size, void* d_ws, size_t ws_size,
                              hipStream_t stream) {
    const float* x = (const float*)d_in[0];
    const float* w = (const float*)d_in[1];
    const float* p = (const float*)d_in[2];
    const float* q = (const float*)d_in[3];
    float* out = (float*)d_out;

    char* ws = (char*)d_ws;
    float*    s      = (float*)ws;                              // 100352 f
    float*    inv_xn = (float*)(ws + 401408);                   // 100352 f
    float*    e      = (float*)(ws + 802816);                   // 128 f
    _Float16* wt     = (_Float16*)(ws + 803328);                // 9*128*64 h
    _Float16* xcl    = (_Float16*)(ws + 950784);                // 32*58*66*64 h

    (void)hipFuncSetAttribute((const void*)k_conv_mfma,
                        hipFuncAttributeMaxDynamicSharedMemorySize, CONV_LDS);

    k_xpose<<<dim3(PH, NB), dim3(256), 0, stream>>>(x, xcl, s);
    k_xnorm<<<dim3(NB * HW / 4 / 256), dim3(256), 0, stream>>>(s, q, inv_xn);
    k_wprep<<<dim3(OUT_C), dim3(64), 0, stream>>>(w, p, q, wt, e);
    k_conv_mfma<<<dim3(14, NB), dim3(512), CONV_LDS, stream>>>(
        xcl, wt, inv_xn, e, out);
}